// Round 8
// baseline (421.202 us; speedup 1.0000x reference)
//
#include <hip/hip_runtime.h>
#include <hip/hip_fp16.h>

#define TT 4
#define BB 32
#define CC 512
#define NN 256
#define DH 64

typedef unsigned char u8;
typedef unsigned short ushort_t;
typedef unsigned int uint_t;
typedef unsigned long long u64;

typedef _Float16 f16;
typedef _Float16 f16x8 __attribute__((ext_vector_type(8)));
typedef float f32x4 __attribute__((ext_vector_type(4)));

// ---- helpers ----------------------------------------------------------
static __device__ __forceinline__ unsigned int pack4(unsigned int w){
  return (w & 1u) | ((w >> 7) & 2u) | ((w >> 14) & 4u) | ((w >> 21) & 8u);
}

// f16 spike-transposed index: [t][b][c/8][n][8]  (element = half)
static __device__ __forceinline__ size_t sidx(int t, int b, int c, int n){
  return ((((size_t)t*BB + b)*(CC/8) + (c>>3))*NN + n)*8 + (c&7);
}

// ---- K0: prep — weight 2-way f16 split + folded BN params -------------
// w = h1 + h2*2^-11: h1 = f16(w); h2 = f16((w-h1)*2048)
__global__ __launch_bounds__(256) void k_prep(
    const float* __restrict__ qw, const float* __restrict__ kw,
    const float* __restrict__ vw, const float* __restrict__ pw,
    const float* __restrict__ bg, const float* __restrict__ bb,
    const float* __restrict__ bm, const float* __restrict__ bv,
    const float* __restrict__ pb, const float* __restrict__ dwcb,
    ushort_t* __restrict__ wsp, float* __restrict__ bn2)
{
  int bid = blockIdx.x;
  if (bid < 4096){
    int idx = bid*256 + threadIdx.x;      // 4 * 512*512
    int g   = idx >> 18;
    int rem = idx & 262143;
    const float* W = (g==0)? qw : (g==1)? kw : (g==2)? vw : pw;
    float wv = W[rem];
    __half h1 = __float2half(wv);
    float h1f = __half2float(h1);
    __half h2 = __float2half((wv - h1f) * 2048.0f);
    size_t base = (size_t)g*2*262144 + rem;
    wsp[base         ] = __half_as_ushort(h1);
    wsp[base + 262144] = __half_as_ushort(h2);
  } else {
    for (int i = threadIdx.x; i < 2560; i += 256){   // 5 BN groups
      int g = i >> 9, d = i & 511;
      float inv = bg[i] / sqrtf(bv[i] + 1e-5f);
      float extra = (g==3)? pb[d] : (g==4)? dwcb[d] : 0.f;
      float bt  = bb[i] - bm[i]*inv + extra*inv;
      bn2[i*2+0] = inv;
      bn2[i*2+1] = bt;
    }
  }
}

// ---- K1: LIF on x -> f16 spikes in k-transposed layout ----------------
__global__ __launch_bounds__(256) void k_lif_x(const float* __restrict__ x,
                                               ushort_t* __restrict__ xs16){
  const int PL = BB*CC*NN;
  int i = (blockIdx.x*256 + threadIdx.x)*4;
  int n = i & (NN-1);
  int c = (i >> 8) & (CC-1);
  int b = i >> 17;
  float4 v = make_float4(0.f,0.f,0.f,0.f);
#pragma unroll
  for (int t=0;t<TT;++t){
    float4 xv = *(const float4*)(x + (size_t)t*PL + i);
    ushort_t s0,s1,s2,s3;
    v.x = v.x + (xv.x - v.x)*0.5f; s0 = (v.x >= 1.0f)? 0x3C00:0; if (s0) v.x = 0.f;
    v.y = v.y + (xv.y - v.y)*0.5f; s1 = (v.y >= 1.0f)? 0x3C00:0; if (s1) v.y = 0.f;
    v.z = v.z + (xv.z - v.z)*0.5f; s2 = (v.z >= 1.0f)? 0x3C00:0; if (s2) v.z = 0.f;
    v.w = v.w + (xv.w - v.w)*0.5f; s3 = (v.w >= 1.0f)? 0x3C00:0; if (s3) v.w = 0.f;
    size_t o = sidx(t, b, c, n);
    xs16[o    ] = s0;
    xs16[o + 8] = s1;
    xs16[o +16] = s2;
    xs16[o +24] = s3;
  }
}

// ---- K2: LDS-free MFMA GEMM (2-pass f16 split) + BN + LIF -------------
// 4 waves/block; wave owns 32d x 64n x 4t.  No LDS, no barriers.
// set: 0=q (f16 per-head transposed out), 1=k, 2=v, 3=proj (u8 out)
__global__ __launch_bounds__(256, 2) void k_gemm16(
    const ushort_t* __restrict__ act16,
    const ushort_t* __restrict__ wsp_all, const float* __restrict__ bn2_all,
    u8* __restrict__ out_k, u8* __restrict__ out_v,
    ushort_t* __restrict__ qt16, u8* __restrict__ out_u8, int set_base)
{
  const int tid = threadIdx.x, l = tid & 63, wvi = tid >> 6;
  const int bx = blockIdx.x, b = blockIdx.y;
  const int set = set_base + blockIdx.z;
  const int dt = (bx >> 2)*4 + wvi;     // 0..15 (32-d tile)
  const int nt = bx & 3;                // 64-n tile
  const ushort_t* wp = wsp_all + (size_t)set*524288;
  const float* bn2 = bn2_all + set*1024;
  const f16 sc = (f16)4.8828125e-4f;    // 2^-11 exact

  // A offset (halves): [sp][d][k]; lane: d = dt*32+df*16+(l&15), k = c0+(l>>4)*8
  const uint_t aO = (uint_t)(dt*32 + (l&15))*512 + (uint_t)(l>>4)*8;
  // B offset (halves): [t][b][c/8][n][8]; lane: cg = c0/8+(l>>4), n = nt*64+nf*16+(l&15)
  uint_t bO[4];
#pragma unroll
  for (int t=0;t<4;++t)
    bO[t] = (((uint_t)t*BB + b)*(CC/8) + (l>>4))*(NN*8) + (uint_t)(nt*64 + (l&15))*8;

  f32x4 acc[2][4][4];
#pragma unroll
  for (int df=0; df<2; ++df)
#pragma unroll
    for (int nf=0; nf<4; ++nf)
#pragma unroll
      for (int t=0; t<4; ++t)
        acc[df][nf][t] = (f32x4){0.f,0.f,0.f,0.f};

  for (int c0 = 0; c0 < CC; c0 += 32){
    f16x8 Af[2][2];
#pragma unroll
    for (int sp=0; sp<2; ++sp)
#pragma unroll
      for (int df=0; df<2; ++df)
        Af[sp][df] = *(const f16x8*)(wp + aO + sp*262144 + df*8192 + c0);
#pragma unroll
    for (int th=0; th<2; ++th){
      f16x8 Bf[4][2];
#pragma unroll
      for (int nf=0; nf<4; ++nf)
#pragma unroll
        for (int t2=0; t2<2; ++t2)
          Bf[nf][t2] = *(const f16x8*)(act16 + bO[th*2+t2] + (uint_t)c0*256 + nf*128);
      // pass 1: h1 * s
#pragma unroll
      for (int df=0; df<2; ++df)
#pragma unroll
        for (int nf=0; nf<4; ++nf)
#pragma unroll
          for (int t2=0; t2<2; ++t2)
            acc[df][nf][th*2+t2] = __builtin_amdgcn_mfma_f32_16x16x32_f16(
                Af[0][df], Bf[nf][t2], acc[df][nf][th*2+t2], 0, 0, 0);
      // pass 2: h2 * (s * 2^-11)
#pragma unroll
      for (int nf=0; nf<4; ++nf)
#pragma unroll
        for (int t2=0; t2<2; ++t2)
          Bf[nf][t2] = Bf[nf][t2] * sc;
#pragma unroll
      for (int df=0; df<2; ++df)
#pragma unroll
        for (int nf=0; nf<4; ++nf)
#pragma unroll
          for (int t2=0; t2<2; ++t2)
            acc[df][nf][th*2+t2] = __builtin_amdgcn_mfma_f32_16x16x32_f16(
                Af[1][df], Bf[nf][t2], acc[df][nf][th*2+t2], 0, 0, 0);
    }
  }

  // ---- epilogue: BN -> LIF(T) -> spikes ----
  if (set == 0){
    // q: f16 per-head transposed [t][b][h][n][d]
#pragma unroll
    for (int df=0; df<2; ++df){
      int dbase = dt*32 + df*16 + ((l>>4)<<2);
      int h = dbase >> 6, dh = dbase & 63;
      float inv4[4], bt4[4];
#pragma unroll
      for (int r=0;r<4;++r){ inv4[r] = bn2[(dbase+r)*2]; bt4[r] = bn2[(dbase+r)*2+1]; }
#pragma unroll
      for (int nf=0; nf<4; ++nf){
        int n = nt*64 + nf*16 + (l&15);
        float vm0=0.f, vm1=0.f, vm2=0.f, vm3=0.f;
#pragma unroll
        for (int t=0; t<4; ++t){
          ushort4 sv;
          float y0 = acc[df][nf][t][0]*inv4[0] + bt4[0];
          vm0 = vm0 + (y0 - vm0)*0.5f; sv.x = (vm0 >= 1.0f)? 0x3C00:0; if (sv.x) vm0 = 0.f;
          float y1 = acc[df][nf][t][1]*inv4[1] + bt4[1];
          vm1 = vm1 + (y1 - vm1)*0.5f; sv.y = (vm1 >= 1.0f)? 0x3C00:0; if (sv.y) vm1 = 0.f;
          float y2 = acc[df][nf][t][2]*inv4[2] + bt4[2];
          vm2 = vm2 + (y2 - vm2)*0.5f; sv.z = (vm2 >= 1.0f)? 0x3C00:0; if (sv.z) vm2 = 0.f;
          float y3 = acc[df][nf][t][3]*inv4[3] + bt4[3];
          vm3 = vm3 + (y3 - vm3)*0.5f; sv.w = (vm3 >= 1.0f)? 0x3C00:0; if (sv.w) vm3 = 0.f;
          *(ushort4*)(qt16 + ((((size_t)t*BB + b)*8 + h)*256 + n)*64 + dh) = sv;
        }
      }
    }
  } else {
    u8* outp = (set==1)? out_k : (set==2)? out_v : out_u8;
#pragma unroll
    for (int df=0; df<2; ++df){
#pragma unroll
      for (int r=0; r<4; ++r){
        int d = dt*32 + df*16 + ((l>>4)<<2) + r;
        float inv = bn2[d*2+0], bt = bn2[d*2+1];
#pragma unroll
        for (int nf=0; nf<4; ++nf){
          int n = nt*64 + nf*16 + (l&15);
          float v = 0.f;
#pragma unroll
          for (int t=0; t<4; ++t){
            float y = acc[df][nf][t][r] * inv + bt;
            v = v + (y - v)*0.5f;
            u8 s = (v >= 1.0f);
            outp[(((size_t)t*BB + b)*CC + d)*NN + n] = s;
            if (s) v = 0.f;
          }
        }
      }
    }
  }
}

// ---- K3: attention per (b,h): kv popcount (exact), o = q@kv via MFMA,
//          LIF(0.5); writes os16 in k-transposed f16 layout -------------
__global__ __launch_bounds__(256, 1) void k_attn(const ushort_t* __restrict__ qt16,
                                                 const u8* __restrict__ ks,
                                                 const u8* __restrict__ vs,
                                                 ushort_t* __restrict__ os16)
{
  const int h = blockIdx.x, b = blockIdx.y;
  __shared__ u64 Kb[64][5];                        // padded rows (40B)
  __shared__ u64 Vb[64][5];
  __shared__ __align__(16) ushort_t kvh[64][88];   // [e][d] f16, padded
  const int tid = threadIdx.x;
  const int l   = tid & 63;
  const int wvi = tid >> 6;

  f32x4 vm[4][4];
#pragma unroll
  for (int nf=0;nf<4;++nf)
#pragma unroll
    for (int ef=0;ef<4;++ef) vm[nf][ef] = (f32x4){0.f,0.f,0.f,0.f};

  for (int t=0;t<TT;++t){
    size_t base  = ((size_t)t*BB + b)*CC*NN + (size_t)h*DH*NN;
    const ushort_t* qtb = qt16 + (((size_t)t*BB + b)*8 + h)*256*64;

    // ---- A-frags (q^T), f16 direct from global ----
    f16x8 aq[4][2];
#pragma unroll
    for (int nf=0; nf<4; ++nf){
      int n = wvi*64 + nf*16 + (l&15);
#pragma unroll
      for (int kf=0; kf<2; ++kf)
        aq[nf][kf] = *(const f16x8*)(qtb + (size_t)n*64 + kf*32 + (l>>4)*8);
    }

    // ---- bitpack K,V: Kb[d] = 256 bits over n ----
#pragma unroll
    for (int p=0;p<4;++p){
      int idx = p*256 + tid;
      int d = idx >> 4;
      int piece = idx & 15;
      uint4 ku = *(const uint4*)(ks + base + (size_t)d*NN + piece*16);
      uint4 vu = *(const uint4*)(vs + base + (size_t)d*NN + piece*16);
      unsigned int kp16 = pack4(ku.x) | (pack4(ku.y)<<4) | (pack4(ku.z)<<8) | (pack4(ku.w)<<12);
      unsigned int vp16 = pack4(vu.x) | (pack4(vu.y)<<4) | (pack4(vu.z)<<8) | (pack4(vu.w)<<12);
      ((ushort_t*)Kb)[d*20 + piece] = (ushort_t)kp16;
      ((ushort_t*)Vb)[d*20 + piece] = (ushort_t)vp16;
    }
    __syncthreads();

    // ---- kv[d][e] popcount -> kvh[e][d] (f16, exact ints <=256) ----
    {
      int dd0 = (tid >> 4)*4, ee0 = (tid & 15)*4;
      int cnt[4][4] = {};
#pragma unroll
      for (int wi=0; wi<4; ++wi){
        u64 kw[4], vw[4];
#pragma unroll
        for (int i=0;i<4;++i) kw[i] = Kb[dd0+i][wi];
#pragma unroll
        for (int j=0;j<4;++j) vw[j] = Vb[ee0+j][wi];
#pragma unroll
        for (int i=0;i<4;++i)
#pragma unroll
          for (int j=0;j<4;++j)
            cnt[i][j] += __popcll(kw[i] & vw[j]);
      }
#pragma unroll
      for (int i=0;i<4;++i)
#pragma unroll
        for (int j=0;j<4;++j)
          kvh[ee0+j][dd0+i] = __half_as_ushort(__float2half((float)cnt[i][j]));
    }
    __syncthreads();

    // ---- o = q @ kv via MFMA (f16); scale, LIF, store f16-transposed ----
    f32x4 acc[4][4];
#pragma unroll
    for (int nf=0;nf<4;++nf)
#pragma unroll
      for (int ef=0;ef<4;++ef) acc[nf][ef] = (f32x4){0.f,0.f,0.f,0.f};

#pragma unroll
    for (int ef=0; ef<4; ++ef){
      f16x8 bv[2];
#pragma unroll
      for (int kf=0; kf<2; ++kf)
        bv[kf] = *(const f16x8*)&kvh[ef*16 + (l&15)][kf*32 + (l>>4)*8];
#pragma unroll
      for (int nf=0; nf<4; ++nf)
#pragma unroll
        for (int kf=0; kf<2; ++kf)
          acc[nf][ef] = __builtin_amdgcn_mfma_f32_16x16x32_f16(
              aq[nf][kf], bv[kf], acc[nf][ef], 0, 0, 0);
    }

#pragma unroll
    for (int nf=0; nf<4; ++nf){
#pragma unroll
      for (int ef=0; ef<4; ++ef){
        int e  = ef*16 + (l&15);
        int n4 = wvi*64 + nf*16 + ((l>>4)<<2);
        size_t o = sidx(t, b, e, n4);
#pragma unroll
        for (int r=0;r<4;++r){
          float ov = acc[nf][ef][r]*0.125f;
          vm[nf][ef][r] += (ov - vm[nf][ef][r])*0.5f;
          ushort_t s = (vm[nf][ef][r] >= 0.5f)? 0x3C00 : 0;
          os16[o + (size_t)r*8] = s;
          if (s) vm[nf][ef][r] = 0.f;
        }
      }
    }
    __syncthreads();   // protect Kb/Vb/kvh for next t
  }
}

// ---- K5: depthwise 5x5 + BN (folded bias) + identity (register rows) --
__global__ __launch_bounds__(256) void k_dwc(const u8* __restrict__ zs,
                                             const float* __restrict__ x,
                                             const float* __restrict__ dwc_w,
                                             const float* __restrict__ bn2,
                                             float* __restrict__ out)
{
  int idx   = blockIdx.x*256 + threadIdx.x;   // TT*BB*CC*16
  int y     = idx & 15;
  int plane = idx >> 4;
  int c     = plane & (CC-1);
  size_t base = (size_t)plane * NN;

  uint4 rows[5];
#pragma unroll
  for (int i=0;i<5;++i){
    int yy = y + i - 2;
    rows[i] = (yy >= 0 && yy < 16) ? *(const uint4*)(zs + base + yy*16)
                                   : make_uint4(0,0,0,0);
  }
  float4 xr[4];
#pragma unroll
  for (int q=0;q<4;++q) xr[q] = *(const float4*)(x + base + y*16 + q*4);

  float wk[25];
  const float* wp = dwc_w + c*25;
#pragma unroll
  for (int i=0;i<25;++i) wk[i] = wp[i];
  float inv = bn2[(2048+c)*2+0], bt = bn2[(2048+c)*2+1];

  float acc[16];
#pragma unroll
  for (int i=0;i<16;++i) acc[i] = 0.f;

#pragma unroll
  for (int i=0;i<5;++i){
    float rb[20];
    rb[0]=0.f; rb[1]=0.f; rb[18]=0.f; rb[19]=0.f;
    uint_t wd[4] = {rows[i].x, rows[i].y, rows[i].z, rows[i].w};
#pragma unroll
    for (int q=0;q<4;++q)
#pragma unroll
      for (int k=0;k<4;++k)
        rb[2 + q*4 + k] = (float)((wd[q] >> (8*k)) & 0xffu);
#pragma unroll
    for (int j=0;j<5;++j){
      float wv = wk[i*5+j];
#pragma unroll
      for (int xp=0;xp<16;++xp)
        acc[xp] = fmaf(wv, rb[xp+j], acc[xp]);
    }
  }

#pragma unroll
  for (int q=0;q<4;++q){
    float4 ov;
    ov.x = acc[q*4+0]*inv + bt + xr[q].x;
    ov.y = acc[q*4+1]*inv + bt + xr[q].y;
    ov.z = acc[q*4+2]*inv + bt + xr[q].z;
    ov.w = acc[q*4+3]*inv + bt + xr[q].w;
    *(float4*)(out + base + y*16 + q*4) = ov;
  }
}

// ---- launch -----------------------------------------------------------
extern "C" void kernel_launch(void* const* d_in, const int* in_sizes, int n_in,
                              void* d_out, int out_size, void* d_ws, size_t ws_size,
                              hipStream_t stream) {
  const float* x      = (const float*)d_in[0];
  const float* q_w    = (const float*)d_in[1];
  const float* k_w    = (const float*)d_in[2];
  const float* v_w    = (const float*)d_in[3];
  const float* proj_w = (const float*)d_in[4];
  const float* proj_b = (const float*)d_in[5];
  const float* dwc_w  = (const float*)d_in[6];
  const float* dwc_b  = (const float*)d_in[7];
  const float* bn_g   = (const float*)d_in[8];
  const float* bn_b   = (const float*)d_in[9];
  const float* bn_m   = (const float*)d_in[10];
  const float* bn_v   = (const float*)d_in[11];
  float* out = (float*)d_out;

  const size_t SZ = (size_t)TT*BB*CC*NN;   // 16,777,216 spikes
  u8* base = (u8*)d_ws;
  ushort_t* xs16 = (ushort_t*)base;                 // 2*SZ bytes; aliased by os16
  ushort_t* os16 = xs16;
  ushort_t* qt16 = (ushort_t*)(base + 2*SZ);        // 2*SZ bytes; aliased by zsp
  u8* zsp = (u8*)qt16;
  u8* ks  = base + 4*SZ;                            // SZ
  u8* vs  = base + 5*SZ;                            // SZ
  ushort_t* wsp = (ushort_t*)(base + 6*SZ);         // 4*2*512*512*2B = 4.2MB
  float* bn2    = (float*)(base + 6*SZ + 4194304);  // 5*512*2 f32

  // 0) prep: weight splits + BN folds
  k_prep<<<4097, 256, 0, stream>>>(q_w, k_w, v_w, proj_w,
      bn_g, bn_b, bn_m, bn_v, proj_b, dwc_b, wsp, bn2);

  // 1) input LIF -> f16 k-transposed spikes
  k_lif_x<<<(BB*CC*NN)/1024, 256, 0, stream>>>(x, xs16);

  // 2) q,k,v in ONE dispatch (z = set): LDS-free MFMA + BN + LIF
  k_gemm16<<<dim3(16, BB, 3), 256, 0, stream>>>(xs16, wsp, bn2,
      ks, vs, qt16, nullptr, 0);

  // 3) attention (exact) + LIF(0.5) -> os16 (overwrites xs16, now dead)
  k_attn<<<dim3(8, BB), 256, 0, stream>>>(qt16, ks, vs, os16);

  // 4) proj: LDS-free MFMA + bias+BN + LIF -> zsp u8 (overwrites qt16, dead)
  k_gemm16<<<dim3(16, BB, 1), 256, 0, stream>>>(os16, wsp, bn2,
      nullptr, nullptr, nullptr, zsp, 3);

  // 5) depthwise conv + BN + residual
  k_dwc<<<(TT*BB*CC*16)/256, 256, 0, stream>>>(zsp, x, dwc_w, bn2, out);
}